// Round 1
// baseline (110.168 us; speedup 1.0000x reference)
//
#include <hip/hip_runtime.h>
#include <hip/hip_bf16.h>

typedef __attribute__((ext_vector_type(8))) short bf16x8;
typedef __attribute__((ext_vector_type(4))) float f32x4;
typedef __attribute__((ext_vector_type(4))) unsigned short u16x4;

static constexpr int D = 256;
static constexpr float INV_T = 2.0f;   // 1 / temperature(0.5)
static constexpr int BM = 256;         // rows per block in k_main (4 waves x 64)
static constexpr int BN = 32;          // cols per step
static constexpr int CSPLIT = 16;      // column splits across grid
static constexpr int LDSP = 264;       // padded LDS pitch in bf16 elements (+8 -> 528B row stride)

__device__ inline unsigned short f2bf(float x) {
    unsigned int u = __builtin_bit_cast(unsigned int, x);
    u += 0x7fffu + ((u >> 16) & 1u);   // round-to-nearest-even
    return (unsigned short)(u >> 16);
}
__device__ inline float bf2f(unsigned short h) {
    unsigned int u = ((unsigned int)h) << 16;
    return __builtin_bit_cast(float, u);
}

// Kernel 1: normalize rows to bf16, init rowsum[i] = -exp(2*selfdot) (diagonal removal)
__global__ void k_norm(const float* __restrict__ zi, const float* __restrict__ zj,
                       unsigned short* __restrict__ zn, float* __restrict__ rowsum,
                       float* __restrict__ pos_sum, int B, int N) {
    int lane = threadIdx.x & 63;
    int wv = threadIdx.x >> 6;
    int row = blockIdx.x * 4 + wv;
    if (blockIdx.x == 0 && threadIdx.x == 0) pos_sum[0] = 0.f;
    if (row >= N) return;
    const float* src = (row < B) ? (zi + (size_t)row * D) : (zj + (size_t)(row - B) * D);
    float4 v = reinterpret_cast<const float4*>(src)[lane];
    float ss = v.x * v.x + v.y * v.y + v.z * v.z + v.w * v.w;
#pragma unroll
    for (int off = 32; off >= 1; off >>= 1) ss += __shfl_xor(ss, off, 64);
    float rn = rsqrtf(ss);
    unsigned short b0 = f2bf(v.x * rn), b1 = f2bf(v.y * rn);
    unsigned short b2 = f2bf(v.z * rn), b3 = f2bf(v.w * rn);
    u16x4 o; o.x = b0; o.y = b1; o.z = b2; o.w = b3;
    *reinterpret_cast<u16x4*>(zn + (size_t)row * D + lane * 4) = o;
    // self-dot with the bf16-rounded values (what the MFMA will see on the diagonal)
    float f0 = bf2f(b0), f1 = bf2f(b1), f2 = bf2f(b2), f3 = bf2f(b3);
    float sd = f0 * f0 + f1 * f1 + f2 * f2 + f3 * f3;
#pragma unroll
    for (int off = 32; off >= 1; off >>= 1) sd += __shfl_xor(sd, off, 64);
    if (lane == 0) rowsum[row] = -__expf(INV_T * sd);
}

// Kernel 2: pos_sum += sum over i<B of (sim[i,i+B] + sim[i+B,i]) = 4*dot
__global__ void k_pos(const unsigned short* __restrict__ zn, float* __restrict__ pos_sum, int B) {
    int lane = threadIdx.x & 63;
    int wv = threadIdx.x >> 6;
    int i = blockIdx.x * 4 + wv;
    if (i >= B) return;
    u16x4 va = *reinterpret_cast<const u16x4*>(zn + (size_t)i * D + lane * 4);
    u16x4 vb = *reinterpret_cast<const u16x4*>(zn + (size_t)(i + B) * D + lane * 4);
    float d = bf2f(va.x) * bf2f(vb.x) + bf2f(va.y) * bf2f(vb.y) +
              bf2f(va.z) * bf2f(vb.z) + bf2f(va.w) * bf2f(vb.w);
#pragma unroll
    for (int off = 32; off >= 1; off >>= 1) d += __shfl_xor(d, off, 64);
    if (lane == 0) atomicAdd(pos_sum, 2.0f * INV_T * d);
}

// Kernel 3: sim tile via MFMA, exp, accumulate row sums.
// Block: 4 waves, each owns 64 rows (A in registers). Streams BN=32 cols/step via LDS.
__global__ __launch_bounds__(256, 2)
void k_main(const unsigned short* __restrict__ zn, float* __restrict__ rowsum, int N) {
    __shared__ __align__(16) unsigned short lds[2][BN][LDSP];
    const int tid = threadIdx.x;
    const int lane = tid & 63, wv = tid >> 6;
    const int l15 = lane & 15, lhi = lane >> 4;
    const int rb = blockIdx.x >> 4;              // row block 0..31
    const int cb = blockIdx.x & (CSPLIT - 1);    // column split 0..15
    const int i0 = rb * BM;
    const int j0base = cb * (N / CSPLIT);
    const int nsteps = (N / CSPLIT) / BN;        // 16

    // A fragments: rows i0 + wv*64 + r*16 + l15, k = kk*32 + lhi*8 (+j), held for whole block
    bf16x8 a[4][8];
    {
        const unsigned short* ab = zn + (size_t)(i0 + wv * 64 + l15) * D + lhi * 8;
#pragma unroll
        for (int r = 0; r < 4; ++r)
#pragma unroll
            for (int kk = 0; kk < 8; ++kk)
                a[r][kk] = *reinterpret_cast<const bf16x8*>(ab + r * 16 * D + kk * 32);
    }

    float rs[4][4];
#pragma unroll
    for (int r = 0; r < 4; ++r)
#pragma unroll
        for (int q = 0; q < 4; ++q) rs[r][q] = 0.f;

    bf16x8 st[4];
    // prologue: stage step 0 into buffer 0
#pragma unroll
    for (int i = 0; i < 4; ++i) {
        int ch = tid + 256 * i;
        int row = ch >> 5, c16 = ch & 31;
        st[i] = *reinterpret_cast<const bf16x8*>(zn + (size_t)(j0base + row) * D + c16 * 8);
    }
#pragma unroll
    for (int i = 0; i < 4; ++i) {
        int ch = tid + 256 * i;
        int row = ch >> 5, c16 = ch & 31;
        *reinterpret_cast<bf16x8*>(&lds[0][row][c16 * 8]) = st[i];
    }
    __syncthreads();

    for (int s = 0; s < nsteps; ++s) {
        const int buf = s & 1;
        if (s + 1 < nsteps) {   // issue next tile's global loads early (hide under MFMA)
            int j0n = j0base + (s + 1) * BN;
#pragma unroll
            for (int i = 0; i < 4; ++i) {
                int ch = tid + 256 * i;
                int row = ch >> 5, c16 = ch & 31;
                st[i] = *reinterpret_cast<const bf16x8*>(zn + (size_t)(j0n + row) * D + c16 * 8);
            }
        }
        f32x4 acc[4][2];
#pragma unroll
        for (int r = 0; r < 4; ++r)
#pragma unroll
            for (int c = 0; c < 2; ++c) acc[r][c] = (f32x4){0.f, 0.f, 0.f, 0.f};

        const unsigned short* bb = &lds[buf][0][0];
#pragma unroll
        for (int kk = 0; kk < 8; ++kk) {
            bf16x8 b0 = *reinterpret_cast<const bf16x8*>(bb + l15 * LDSP + kk * 32 + lhi * 8);
            bf16x8 b1 = *reinterpret_cast<const bf16x8*>(bb + (16 + l15) * LDSP + kk * 32 + lhi * 8);
#pragma unroll
            for (int r = 0; r < 4; ++r) {
                acc[r][0] = __builtin_amdgcn_mfma_f32_16x16x32_bf16(a[r][kk], b0, acc[r][0], 0, 0, 0);
                acc[r][1] = __builtin_amdgcn_mfma_f32_16x16x32_bf16(a[r][kk], b1, acc[r][1], 0, 0, 0);
            }
        }
        // epilogue: exp + rowsum accumulate (no diagonal masking needed — handled in k_norm)
#pragma unroll
        for (int r = 0; r < 4; ++r)
#pragma unroll
            for (int c = 0; c < 2; ++c)
#pragma unroll
                for (int q = 0; q < 4; ++q)
                    rs[r][q] += __expf(INV_T * acc[r][c][q]);

        if (s + 1 < nsteps) {   // write next tile into the other buffer
#pragma unroll
            for (int i = 0; i < 4; ++i) {
                int ch = tid + 256 * i;
                int row = ch >> 5, c16 = ch & 31;
                *reinterpret_cast<bf16x8*>(&lds[buf ^ 1][row][c16 * 8]) = st[i];
            }
        }
        __syncthreads();
    }

    // reduce rs across the 16 lanes sharing each row, then one atomic per row
#pragma unroll
    for (int r = 0; r < 4; ++r)
#pragma unroll
        for (int q = 0; q < 4; ++q) {
            float v = rs[r][q];
            v += __shfl_xor(v, 1, 64);
            v += __shfl_xor(v, 2, 64);
            v += __shfl_xor(v, 4, 64);
            v += __shfl_xor(v, 8, 64);
            if (l15 == 0)
                atomicAdd(&rowsum[i0 + wv * 64 + r * 16 + lhi * 4 + q], v);
        }
}

// Kernel 4: loss = (sum_i log(rowsum_i) - pos_sum) / N
__global__ void k_final(const float* __restrict__ rowsum, const float* __restrict__ pos_sum,
                        float* __restrict__ out, int N) {
    __shared__ float red[4];
    int lane = threadIdx.x & 63, wv = threadIdx.x >> 6;
    float local = 0.f;
    for (int i = threadIdx.x; i < N; i += 256) local += __logf(rowsum[i]);
#pragma unroll
    for (int off = 32; off >= 1; off >>= 1) local += __shfl_xor(local, off, 64);
    if (lane == 0) red[wv] = local;
    __syncthreads();
    if (threadIdx.x == 0) {
        float t = red[0] + red[1] + red[2] + red[3];
        out[0] = (t - pos_sum[0]) / (float)N;
    }
}

extern "C" void kernel_launch(void* const* d_in, const int* in_sizes, int n_in,
                              void* d_out, int out_size, void* d_ws, size_t ws_size,
                              hipStream_t stream) {
    const float* zi = (const float*)d_in[0];
    const float* zj = (const float*)d_in[1];
    const int B = in_sizes[0] / D;   // 4096
    const int N = 2 * B;             // 8192

    unsigned short* zn = (unsigned short*)d_ws;                       // N*D bf16 = 4 MB
    float* rowsum = (float*)((char*)d_ws + (size_t)N * D * 2);        // N floats
    float* pos_sum = rowsum + N;                                      // 1 float

    float* out = (float*)d_out;

    hipLaunchKernelGGL(k_norm, dim3(N / 4), dim3(256), 0, stream, zi, zj, zn, rowsum, pos_sum, B, N);
    hipLaunchKernelGGL(k_pos, dim3(B / 4), dim3(256), 0, stream, zn, pos_sum, B);
    hipLaunchKernelGGL(k_main, dim3((N / BM) * CSPLIT), dim3(256), 0, stream, zn, rowsum, N);
    hipLaunchKernelGGL(k_final, dim3(1), dim3(256), 0, stream, rowsum, pos_sum, out, N);
}

// Round 2
// 58.176 us; speedup vs baseline: 1.8937x; 1.8937x over previous
//
#include <hip/hip_runtime.h>
#include <hip/hip_bf16.h>

typedef __attribute__((ext_vector_type(8))) short bf16x8;
typedef __attribute__((ext_vector_type(4))) float f32x4;
typedef __attribute__((ext_vector_type(4))) unsigned short u16x4;

static constexpr int D = 256;
static constexpr float INV_T = 2.0f;   // 1 / temperature(0.5)
static constexpr int BM = 256;         // rows per block in k_main (4 waves x 64)
static constexpr int BN = 32;          // cols per step
static constexpr int CSPLIT = 16;      // column splits across grid
static constexpr int LDSP = 264;       // padded LDS pitch in bf16 elements (+8 -> 528B row stride)

__device__ inline unsigned short f2bf(float x) {
    unsigned int u = __builtin_bit_cast(unsigned int, x);
    u += 0x7fffu + ((u >> 16) & 1u);   // round-to-nearest-even
    return (unsigned short)(u >> 16);
}
__device__ inline float bf2f(unsigned short h) {
    unsigned int u = ((unsigned int)h) << 16;
    return __builtin_bit_cast(float, u);
}

// Kernel 1: per pair i in [0,B): normalize rows i and i+B to bf16,
// rowsum init = -exp(2*selfdot) (diagonal removal), and the positive-pair
// dot -> per-block partial (NO global atomics; k_pos's single-address
// atomicAdd was 4096 serialized atomics = 54us).
__global__ void k_norm(const float* __restrict__ zi, const float* __restrict__ zj,
                       unsigned short* __restrict__ zn, float* __restrict__ rowsum,
                       float* __restrict__ pos_partial, int B) {
    __shared__ float red[4];
    const int lane = threadIdx.x & 63;
    const int wv = threadIdx.x >> 6;
    const int i = blockIdx.x * 4 + wv;       // pair index
    if (i < B) {
        float4 vi = reinterpret_cast<const float4*>(zi + (size_t)i * D)[lane];
        float4 vj = reinterpret_cast<const float4*>(zj + (size_t)i * D)[lane];
        float ssi = vi.x * vi.x + vi.y * vi.y + vi.z * vi.z + vi.w * vi.w;
        float ssj = vj.x * vj.x + vj.y * vj.y + vj.z * vj.z + vj.w * vj.w;
#pragma unroll
        for (int off = 32; off >= 1; off >>= 1) {
            ssi += __shfl_xor(ssi, off, 64);
            ssj += __shfl_xor(ssj, off, 64);
        }
        float rni = rsqrtf(ssi), rnj = rsqrtf(ssj);
        unsigned short a0 = f2bf(vi.x * rni), a1 = f2bf(vi.y * rni);
        unsigned short a2 = f2bf(vi.z * rni), a3 = f2bf(vi.w * rni);
        unsigned short b0 = f2bf(vj.x * rnj), b1 = f2bf(vj.y * rnj);
        unsigned short b2 = f2bf(vj.z * rnj), b3 = f2bf(vj.w * rnj);
        u16x4 oa; oa.x = a0; oa.y = a1; oa.z = a2; oa.w = a3;
        u16x4 ob; ob.x = b0; ob.y = b1; ob.z = b2; ob.w = b3;
        *reinterpret_cast<u16x4*>(zn + (size_t)i * D + lane * 4) = oa;
        *reinterpret_cast<u16x4*>(zn + (size_t)(i + B) * D + lane * 4) = ob;
        // self-dots + pair-dot with the bf16-rounded values (match MFMA exactly)
        float fa0 = bf2f(a0), fa1 = bf2f(a1), fa2 = bf2f(a2), fa3 = bf2f(a3);
        float fb0 = bf2f(b0), fb1 = bf2f(b1), fb2 = bf2f(b2), fb3 = bf2f(b3);
        float sdi = fa0 * fa0 + fa1 * fa1 + fa2 * fa2 + fa3 * fa3;
        float sdj = fb0 * fb0 + fb1 * fb1 + fb2 * fb2 + fb3 * fb3;
        float pd  = fa0 * fb0 + fa1 * fb1 + fa2 * fb2 + fa3 * fb3;
#pragma unroll
        for (int off = 32; off >= 1; off >>= 1) {
            sdi += __shfl_xor(sdi, off, 64);
            sdj += __shfl_xor(sdj, off, 64);
            pd  += __shfl_xor(pd, off, 64);
        }
        if (lane == 0) {
            rowsum[i]     = -__expf(INV_T * sdi);
            rowsum[i + B] = -__expf(INV_T * sdj);
            red[wv] = pd;
        }
    } else if (lane == 0) {
        red[wv] = 0.f;
    }
    __syncthreads();
    if (threadIdx.x == 0)
        pos_partial[blockIdx.x] = 2.0f * INV_T * (red[0] + red[1] + red[2] + red[3]);
}

// Kernel 2: sim tile via MFMA, exp, accumulate row sums.
// Block: 4 waves, each owns 64 rows (A in registers). Streams BN=32 cols/step via LDS.
__global__ __launch_bounds__(256, 2)
void k_main(const unsigned short* __restrict__ zn, float* __restrict__ rowsum, int N) {
    __shared__ __align__(16) unsigned short lds[2][BN][LDSP];
    const int tid = threadIdx.x;
    const int lane = tid & 63, wv = tid >> 6;
    const int l15 = lane & 15, lhi = lane >> 4;
    const int rb = blockIdx.x >> 4;              // row block 0..31
    const int cb = blockIdx.x & (CSPLIT - 1);    // column split 0..15
    const int i0 = rb * BM;
    const int j0base = cb * (N / CSPLIT);
    const int nsteps = (N / CSPLIT) / BN;        // 16

    // A fragments: rows i0 + wv*64 + r*16 + l15, k = kk*32 + lhi*8 (+j), held for whole block
    bf16x8 a[4][8];
    {
        const unsigned short* ab = zn + (size_t)(i0 + wv * 64 + l15) * D + lhi * 8;
#pragma unroll
        for (int r = 0; r < 4; ++r)
#pragma unroll
            for (int kk = 0; kk < 8; ++kk)
                a[r][kk] = *reinterpret_cast<const bf16x8*>(ab + r * 16 * D + kk * 32);
    }

    float rs[4][4];
#pragma unroll
    for (int r = 0; r < 4; ++r)
#pragma unroll
        for (int q = 0; q < 4; ++q) rs[r][q] = 0.f;

    bf16x8 st[4];
    // prologue: stage step 0 into buffer 0
#pragma unroll
    for (int i = 0; i < 4; ++i) {
        int ch = tid + 256 * i;
        int row = ch >> 5, c16 = ch & 31;
        st[i] = *reinterpret_cast<const bf16x8*>(zn + (size_t)(j0base + row) * D + c16 * 8);
    }
#pragma unroll
    for (int i = 0; i < 4; ++i) {
        int ch = tid + 256 * i;
        int row = ch >> 5, c16 = ch & 31;
        *reinterpret_cast<bf16x8*>(&lds[0][row][c16 * 8]) = st[i];
    }
    __syncthreads();

    for (int s = 0; s < nsteps; ++s) {
        const int buf = s & 1;
        if (s + 1 < nsteps) {   // issue next tile's global loads early (hide under MFMA)
            int j0n = j0base + (s + 1) * BN;
#pragma unroll
            for (int i = 0; i < 4; ++i) {
                int ch = tid + 256 * i;
                int row = ch >> 5, c16 = ch & 31;
                st[i] = *reinterpret_cast<const bf16x8*>(zn + (size_t)(j0n + row) * D + c16 * 8);
            }
        }
        f32x4 acc[4][2];
#pragma unroll
        for (int r = 0; r < 4; ++r)
#pragma unroll
            for (int c = 0; c < 2; ++c) acc[r][c] = (f32x4){0.f, 0.f, 0.f, 0.f};

        const unsigned short* bb = &lds[buf][0][0];
#pragma unroll
        for (int kk = 0; kk < 8; ++kk) {
            bf16x8 b0 = *reinterpret_cast<const bf16x8*>(bb + l15 * LDSP + kk * 32 + lhi * 8);
            bf16x8 b1 = *reinterpret_cast<const bf16x8*>(bb + (16 + l15) * LDSP + kk * 32 + lhi * 8);
#pragma unroll
            for (int r = 0; r < 4; ++r) {
                acc[r][0] = __builtin_amdgcn_mfma_f32_16x16x32_bf16(a[r][kk], b0, acc[r][0], 0, 0, 0);
                acc[r][1] = __builtin_amdgcn_mfma_f32_16x16x32_bf16(a[r][kk], b1, acc[r][1], 0, 0, 0);
            }
        }
        // epilogue: exp + rowsum accumulate (no diagonal masking needed — handled in k_norm)
#pragma unroll
        for (int r = 0; r < 4; ++r)
#pragma unroll
            for (int c = 0; c < 2; ++c)
#pragma unroll
                for (int q = 0; q < 4; ++q)
                    rs[r][q] += __expf(INV_T * acc[r][c][q]);

        if (s + 1 < nsteps) {   // write next tile into the other buffer
#pragma unroll
            for (int i = 0; i < 4; ++i) {
                int ch = tid + 256 * i;
                int row = ch >> 5, c16 = ch & 31;
                *reinterpret_cast<bf16x8*>(&lds[buf ^ 1][row][c16 * 8]) = st[i];
            }
        }
        __syncthreads();
    }

    // reduce rs across the 16 lanes sharing each row, then one atomic per row
    // (16 column-split blocks hit DISTINCT addresses per row -> no contention)
#pragma unroll
    for (int r = 0; r < 4; ++r)
#pragma unroll
        for (int q = 0; q < 4; ++q) {
            float v = rs[r][q];
            v += __shfl_xor(v, 1, 64);
            v += __shfl_xor(v, 2, 64);
            v += __shfl_xor(v, 4, 64);
            v += __shfl_xor(v, 8, 64);
            if (l15 == 0)
                atomicAdd(&rowsum[i0 + wv * 64 + r * 16 + lhi * 4 + q], v);
        }
}

// Kernel 3: loss = (sum_i log(rowsum_i) - sum_b pos_partial_b) / N
__global__ void k_final(const float* __restrict__ rowsum, const float* __restrict__ pos_partial,
                        int n_partial, float* __restrict__ out, int N) {
    __shared__ float red[4];
    int lane = threadIdx.x & 63, wv = threadIdx.x >> 6;
    float local = 0.f;
    for (int i = threadIdx.x; i < N; i += 256) local += __logf(rowsum[i]);
    for (int i = threadIdx.x; i < n_partial; i += 256) local -= pos_partial[i];
#pragma unroll
    for (int off = 32; off >= 1; off >>= 1) local += __shfl_xor(local, off, 64);
    if (lane == 0) red[wv] = local;
    __syncthreads();
    if (threadIdx.x == 0) {
        out[0] = (red[0] + red[1] + red[2] + red[3]) / (float)N;
    }
}

extern "C" void kernel_launch(void* const* d_in, const int* in_sizes, int n_in,
                              void* d_out, int out_size, void* d_ws, size_t ws_size,
                              hipStream_t stream) {
    const float* zi = (const float*)d_in[0];
    const float* zj = (const float*)d_in[1];
    const int B = in_sizes[0] / D;   // 4096
    const int N = 2 * B;             // 8192

    unsigned short* zn = (unsigned short*)d_ws;                       // N*D bf16 = 4 MB
    float* rowsum = (float*)((char*)d_ws + (size_t)N * D * 2);        // N floats
    float* pos_partial = rowsum + N;                                  // B/4 floats

    float* out = (float*)d_out;

    const int npb = B / 4;  // k_norm blocks == pos partials
    hipLaunchKernelGGL(k_norm, dim3(npb), dim3(256), 0, stream, zi, zj, zn, rowsum, pos_partial, B);
    hipLaunchKernelGGL(k_main, dim3((N / BM) * CSPLIT), dim3(256), 0, stream, zn, rowsum, N);
    hipLaunchKernelGGL(k_final, dim3(1), dim3(256), 0, stream, rowsum, pos_partial, npb, out, N);
}